// Round 1
// baseline (359.932 us; speedup 1.0000x reference)
//
#include <hip/hip_runtime.h>
#include <float.h>

#define N_PTS   48
#define N_PAIRS 1128
#define C_TOT   2256
#define NE      46
#define DOC     277
#define DCOMB   286
#define DGRAPH  289
#define BATCH   4

// ---------------- prep kernels ----------------

__global__ void center_kernel(const float* __restrict__ x, float* __restrict__ xc) {
    int row = blockIdx.x;              // 12 rows = b*3+d
    int t = threadIdx.x;               // 64 threads
    float v = (t < N_PTS) ? x[row * N_PTS + t] : 0.f;
    float s = v;
    #pragma unroll
    for (int m = 32; m >= 1; m >>= 1) s += __shfl_xor(s, m);
    if (t < N_PTS) xc[row * N_PTS + t] = v - s * (1.0f / N_PTS);
}

// out[c*R + r] = in[r*C + c]
__global__ void transpose_kernel(const float* __restrict__ in, float* __restrict__ out,
                                 int R, int C) {
    int idx = blockIdx.x * blockDim.x + threadIdx.x;
    if (idx < R * C) {
        int r = idx / C, c = idx % C;
        out[c * R + r] = in[idx];
    }
}

// ---------------- stage 1: per-pair kernel ----------------

__device__ __forceinline__ void bitonic64(float p[64]) {
    #pragma unroll
    for (int k = 2; k <= 64; k <<= 1) {
        #pragma unroll
        for (int j = k >> 1; j > 0; j >>= 1) {
            #pragma unroll
            for (int i = 0; i < 64; i++) {
                int l = i ^ j;
                if (l > i) {
                    bool up = ((i & k) == 0);
                    float a = p[i], b = p[l];
                    float lo = fminf(a, b), hi = fmaxf(a, b);
                    p[i] = up ? lo : hi;
                    p[l] = up ? hi : lo;
                }
            }
        }
    }
}

__global__ __launch_bounds__(64) void pair_kernel(
        const float* __restrict__ xc, const float* __restrict__ A_comb,
        const float* __restrict__ wcT, float* __restrict__ gv) {
    int blk = blockIdx.x;
    int b = blk / C_TOT, c = blk % C_TOT;
    int t = threadIdx.x;

    __shared__ float Xs[3][N_PTS];
    __shared__ float MtVs[3][NE];
    __shared__ float Ms[3][3];

    for (int idx = t; idx < 3 * N_PTS; idx += 64)
        ((float*)Xs)[idx] = xc[b * 3 * N_PTS + idx];
    __syncthreads();

    // decode ordered pair c -> (first, second); i<j is the sorted pair
    int cc = c % N_PAIRS;
    bool rev = c >= N_PAIRS;
    int i = 0, rem = cc;
    while (rem >= N_PTS - 1 - i) { rem -= N_PTS - 1 - i; i++; }
    int j = i + 1 + rem;
    int first = rev ? j : i, second = rev ? i : j;

    float a0 = Xs[0][first], a1 = Xs[1][first], a2 = Xs[2][first];
    float b0 = Xs[0][second], b1 = Xs[1][second], b2 = Xs[2][second];
    float c0 = a1 * b2 - a2 * b1;
    float c1 = a2 * b0 - a0 * b2;
    float c2 = a0 * b1 - a1 * b0;

    if (t == 0) {
        Ms[0][0] = a0; Ms[0][1] = a1; Ms[0][2] = a2;
        Ms[1][0] = b0; Ms[1][1] = b1; Ms[1][2] = b2;
        Ms[2][0] = c0; Ms[2][1] = c1; Ms[2][2] = c2;
    }
    if (t < NE) {
        int m = t;
        int a = (m < i) ? m : m + 1;     // complement index (skip i, then j; i<j)
        a = (a < j) ? a : a + 1;
        float v0 = Xs[0][a], v1 = Xs[1][a], v2 = Xs[2][a];
        MtVs[0][t] = a0 * v0 + a1 * v1 + a2 * v2;
        MtVs[1][t] = b0 * v0 + b1 * v1 + b2 * v2;
        MtVs[2][t] = c0 * v0 + c1 * v1 + c2 * v2;
    }
    __syncthreads();

    size_t base = ((size_t)b * DCOMB) * C_TOT + c;

    if (t < 9) {                         // vec1 = MtM flattened [k][l]
        int k = t / 3, l = t % 3;
        float d = Ms[k][0] * Ms[l][0] + Ms[k][1] * Ms[l][1] + Ms[k][2] * Ms[l][2];
        gv[base + (size_t)t * C_TOT] = d;
    }

    for (int e = t; e < DOC; e += 64) {
        float A0 = A_comb[e], A1 = A_comb[DOC + e], A2 = A_comb[2 * DOC + e];
        float p[64];
        #pragma unroll
        for (int n = 0; n < NE; n++)
            p[n] = A0 * MtVs[0][n] + A1 * MtVs[1][n] + A2 * MtVs[2][n];
        #pragma unroll
        for (int n = NE; n < 64; n++) p[n] = FLT_MAX;
        bitonic64(p);
        float acc = 0.f;
        const float* w = wcT + e * NE;
        #pragma unroll
        for (int n = 0; n < NE; n++) acc += p[n] * w[n];
        gv[base + (size_t)(9 + e) * C_TOT] = acc;
    }
}

// ---------------- stage 2: global kernel ----------------

__global__ __launch_bounds__(256) void graph_kernel(
        const float* __restrict__ gv, const float* __restrict__ A_graph,
        const float* __restrict__ wgT, float* __restrict__ out) {
    int blk = blockIdx.x;
    int b = blk / DGRAPH, e = blk % DGRAPH;
    int tid = threadIdx.x;

    __shared__ float Acol[DCOMB];
    __shared__ float s[4096];
    __shared__ float red[256];

    for (int d = tid; d < DCOMB; d += 256) Acol[d] = A_graph[d * DGRAPH + e];
    __syncthreads();

    const float* g = gv + (size_t)b * DCOMB * C_TOT;
    for (int ci = tid; ci < 4096; ci += 256) {
        float acc;
        if (ci < C_TOT) {
            acc = 0.f;
            const float* gp = g + ci;
            for (int d = 0; d < DCOMB; d++) acc += Acol[d] * gp[(size_t)d * C_TOT];
        } else {
            acc = FLT_MAX;
        }
        s[ci] = acc;
    }

    // bitonic sort of 4096 in LDS (ascending)
    for (int k = 2; k <= 4096; k <<= 1) {
        for (int j = k >> 1; j > 0; j >>= 1) {
            __syncthreads();
            for (int idx = tid; idx < 2048; idx += 256) {
                int i2 = ((idx & ~(j - 1)) << 1) | (idx & (j - 1));
                int l = i2 | j;
                bool up = ((i2 & k) == 0);
                float a = s[i2], bb = s[l];
                if ((a > bb) == up) { s[i2] = bb; s[l] = a; }
            }
        }
    }
    __syncthreads();

    float acc = 0.f;
    const float* w = wgT + (size_t)e * C_TOT;
    for (int n = tid; n < C_TOT; n += 256) acc += s[n] * w[n];
    red[tid] = acc;
    __syncthreads();
    for (int off = 128; off >= 1; off >>= 1) {
        if (tid < off) red[tid] += red[tid + off];
        __syncthreads();
    }
    if (tid == 0) out[b * DGRAPH + e] = red[0];
}

// ---------------- launch ----------------

extern "C" void kernel_launch(void* const* d_in, const int* in_sizes, int n_in,
                              void* d_out, int out_size, void* d_ws, size_t ws_size,
                              hipStream_t stream) {
    const float* x       = (const float*)d_in[0];
    const float* A_comb  = (const float*)d_in[1];
    const float* w_comb  = (const float*)d_in[2];
    const float* A_graph = (const float*)d_in[3];
    const float* w_graph = (const float*)d_in[4];
    float* out = (float*)d_out;

    float* ws  = (float*)d_ws;
    float* xc  = ws;                         // 576
    float* wcT = xc + 576;                   // 277*46   = 12742
    float* wgT = wcT + 12742;                // 289*2256 = 651984
    float* gv  = wgT + 651984;               // 4*286*2256 = 2580864

    center_kernel<<<12, 64, 0, stream>>>(x, xc);
    transpose_kernel<<<(NE * DOC + 255) / 256, 256, 0, stream>>>(w_comb, wcT, NE, DOC);
    transpose_kernel<<<(C_TOT * DGRAPH + 255) / 256, 256, 0, stream>>>(w_graph, wgT, C_TOT, DGRAPH);
    pair_kernel<<<BATCH * C_TOT, 64, 0, stream>>>(xc, A_comb, wcT, gv);
    graph_kernel<<<BATCH * DGRAPH, 256, 0, stream>>>(gv, A_graph, wgT, out);
}

// Round 2
// 323.195 us; speedup vs baseline: 1.1137x; 1.1137x over previous
//
#include <hip/hip_runtime.h>
#include <float.h>

#define N_PTS   48
#define N_PAIRS 1128
#define C_TOT   2256
#define NE      46
#define DOC     277
#define DCOMB   286
#define GSTRIDE 288
#define DGRAPH  289
#define BATCH   4

// ---------------- prep kernels ----------------

__global__ void center_kernel(const float* __restrict__ x, float* __restrict__ xc) {
    int row = blockIdx.x;              // 12 rows = b*3+d
    int t = threadIdx.x;               // 64 threads
    float v = (t < N_PTS) ? x[row * N_PTS + t] : 0.f;
    float s = v;
    #pragma unroll
    for (int m = 32; m >= 1; m >>= 1) s += __shfl_xor(s, m);
    if (t < N_PTS) xc[row * N_PTS + t] = v - s * (1.0f / N_PTS);
}

// LDS-tiled transpose: out[c*R + r] = in[r*C + c]
__global__ __launch_bounds__(256) void transpose_tiled(const float* __restrict__ in,
                                                       float* __restrict__ out, int R, int C) {
    __shared__ float tile[32][33];
    int r0 = blockIdx.x * 32, c0 = blockIdx.y * 32;
    int tx = threadIdx.x & 31, ty = threadIdx.x >> 5;   // 32 x 8
    #pragma unroll
    for (int yy = 0; yy < 4; yy++) {
        int r = r0 + ty + 8 * yy, c = c0 + tx;
        tile[ty + 8 * yy][tx] = (r < R && c < C) ? in[r * C + c] : 0.f;
    }
    __syncthreads();
    #pragma unroll
    for (int yy = 0; yy < 4; yy++) {
        int c = c0 + ty + 8 * yy, r = r0 + tx;
        if (c < C && r < R) out[(size_t)c * R + r] = tile[tx][ty + 8 * yy];
    }
}

// ---------------- stage 1: per-pair kernel ----------------

__device__ __forceinline__ void bitonic64(float p[64]) {
    #pragma unroll
    for (int k = 2; k <= 64; k <<= 1) {
        #pragma unroll
        for (int j = k >> 1; j > 0; j >>= 1) {
            #pragma unroll
            for (int i = 0; i < 64; i++) {
                int l = i ^ j;
                if (l > i) {
                    bool up = ((i & k) == 0);
                    float a = p[i], b = p[l];
                    float lo = fminf(a, b), hi = fmaxf(a, b);
                    p[i] = up ? lo : hi;
                    p[l] = up ? hi : lo;
                }
            }
        }
    }
}

__global__ __launch_bounds__(64) void pair_kernel(
        const float* __restrict__ xc, const float* __restrict__ A_comb,
        const float* __restrict__ w_comb, float* __restrict__ gvR) {
    int blk = blockIdx.x;
    int b = blk / C_TOT, c = blk % C_TOT;
    int t = threadIdx.x;

    __shared__ float Xs[3][N_PTS];
    __shared__ float MtVs[3][NE];
    __shared__ float Ms[3][3];
    __shared__ float rowv[GSTRIDE];

    for (int idx = t; idx < 3 * N_PTS; idx += 64)
        ((float*)Xs)[idx] = xc[b * 3 * N_PTS + idx];
    if (t < 2) rowv[DCOMB + t] = 0.f;
    __syncthreads();

    // decode ordered pair c -> (first, second); i<j is the sorted pair
    int cc = c % N_PAIRS;
    bool rev = c >= N_PAIRS;
    int i = 0, rem = cc;
    while (rem >= N_PTS - 1 - i) { rem -= N_PTS - 1 - i; i++; }
    int j = i + 1 + rem;
    int first = rev ? j : i, second = rev ? i : j;

    float a0 = Xs[0][first], a1 = Xs[1][first], a2 = Xs[2][first];
    float b0 = Xs[0][second], b1 = Xs[1][second], b2 = Xs[2][second];
    float c0 = a1 * b2 - a2 * b1;
    float c1 = a2 * b0 - a0 * b2;
    float c2 = a0 * b1 - a1 * b0;

    if (t == 0) {
        Ms[0][0] = a0; Ms[0][1] = a1; Ms[0][2] = a2;
        Ms[1][0] = b0; Ms[1][1] = b1; Ms[1][2] = b2;
        Ms[2][0] = c0; Ms[2][1] = c1; Ms[2][2] = c2;
    }
    if (t < NE) {
        int m = t;
        int a = (m < i) ? m : m + 1;     // complement index (skip i, then j; i<j)
        a = (a < j) ? a : a + 1;
        float v0 = Xs[0][a], v1 = Xs[1][a], v2 = Xs[2][a];
        MtVs[0][t] = a0 * v0 + a1 * v1 + a2 * v2;
        MtVs[1][t] = b0 * v0 + b1 * v1 + b2 * v2;
        MtVs[2][t] = c0 * v0 + c1 * v1 + c2 * v2;
    }
    __syncthreads();

    if (t < 9) {                         // vec1 = MtM flattened [k][l]
        int k = t / 3, l = t % 3;
        rowv[t] = Ms[k][0] * Ms[l][0] + Ms[k][1] * Ms[l][1] + Ms[k][2] * Ms[l][2];
    }

    for (int e = t; e < DOC; e += 64) {
        float A0 = A_comb[e], A1 = A_comb[DOC + e], A2 = A_comb[2 * DOC + e];
        float p[64];
        #pragma unroll
        for (int n = 0; n < NE; n++)
            p[n] = A0 * MtVs[0][n] + A1 * MtVs[1][n] + A2 * MtVs[2][n];
        #pragma unroll
        for (int n = NE; n < 64; n++) p[n] = FLT_MAX;
        bitonic64(p);
        float acc = 0.f;
        #pragma unroll
        for (int n = 0; n < NE; n++) acc += p[n] * w_comb[n * DOC + e];  // coalesced over lanes
        rowv[9 + e] = acc;
    }
    __syncthreads();

    // coalesced row write: gvR[b][c][0..287]
    float* dst = gvR + ((size_t)b * C_TOT + c) * GSTRIDE;
    for (int idx = t; idx < GSTRIDE; idx += 64) dst[idx] = rowv[idx];
}

// ---------------- stage 2a: projection GEMM ----------------
// P[b][e][c] = sum_d A_graph[d][e] * gvR[b][c][d]
#define KT 32

__global__ __launch_bounds__(256) void proj_gemm(
        const float* __restrict__ gvR, const float* __restrict__ A_graph,
        float* __restrict__ P) {
    __shared__ __align__(16) float As[KT][64];
    __shared__ __align__(16) float Gs[KT][68];
    int b = blockIdx.z;
    int e0 = blockIdx.y * 64;
    int c0 = blockIdx.x * 64;
    int tid = threadIdx.x;
    int tx = tid & 15, ty = tid >> 4;
    float acc[4][4] = {};
    const float* gbase = gvR + (size_t)b * C_TOT * GSTRIDE;

    for (int k0 = 0; k0 < GSTRIDE; k0 += KT) {
        #pragma unroll
        for (int o = 0; o < 8; o++) {
            int idx = o * 256 + tid;
            int kk = idx >> 6, ee = idx & 63;
            int k = k0 + kk, E = e0 + ee;
            As[kk][ee] = (k < DCOMB && E < DGRAPH) ? A_graph[k * DGRAPH + E] : 0.f;
        }
        int kk = tid & 31;
        int cb = tid >> 5;   // 0..7
        #pragma unroll
        for (int o = 0; o < 8; o++) {
            int ccol = o * 8 + cb;
            int C = c0 + ccol;
            Gs[kk][ccol] = (C < C_TOT) ? gbase[(size_t)C * GSTRIDE + k0 + kk] : 0.f;
        }
        __syncthreads();
        #pragma unroll
        for (int k = 0; k < KT; k++) {
            float4 av = *(const float4*)&As[k][ty * 4];
            float4 gq = *(const float4*)&Gs[k][tx * 4];
            float ar[4] = {av.x, av.y, av.z, av.w};
            float gr[4] = {gq.x, gq.y, gq.z, gq.w};
            #pragma unroll
            for (int ii = 0; ii < 4; ii++)
                #pragma unroll
                for (int jj = 0; jj < 4; jj++)
                    acc[ii][jj] += ar[ii] * gr[jj];
        }
        __syncthreads();
    }
    #pragma unroll
    for (int ii = 0; ii < 4; ii++) {
        int e = e0 + ty * 4 + ii;
        int c = c0 + tx * 4;
        if (e < DGRAPH && c < C_TOT) {     // C_TOT % 4 == 0 -> full float4 in-range
            float4 val = make_float4(acc[ii][0], acc[ii][1], acc[ii][2], acc[ii][3]);
            *(float4*)&P[((size_t)b * DGRAPH + e) * C_TOT + c] = val;
        }
    }
}

// ---------------- stage 2b: in-register wave bitonic sort + dot ----------------
// layout: global index g = 64*lane + r  (lane owns 64 consecutive sorted slots)

__device__ __forceinline__ void ce_rt(float& a, float& b, bool up) {
    float lo = fminf(a, b), hi = fmaxf(a, b);
    a = up ? lo : hi;
    b = up ? hi : lo;
}

template<int J, int K>
__device__ __forceinline__ void pass_inlane(float v[64], int lane) {
    bool upl = (K >= 64) ? ((lane & (K >> 6)) == 0) : true;
    #pragma unroll
    for (int r = 0; r < 64; r++) {
        int l = r ^ J;
        if (l > r) {
            if (K < 64) {
                bool up = ((r & K) == 0);   // compile-time
                float a = v[r], b = v[l];
                float lo = fminf(a, b), hi = fmaxf(a, b);
                v[r] = up ? lo : hi;
                v[l] = up ? hi : lo;
            } else {
                ce_rt(v[r], v[l], upl);
            }
        }
    }
}

template<int JL, int K>
__device__ __forceinline__ void pass_cross(float v[64], int lane) {
    bool lower = (lane & JL) == 0;
    bool up = (lane & (K >> 6)) == 0;
    bool keep_min = (lower == up);
    #pragma unroll
    for (int r = 0; r < 64; r++) {
        float pv = __shfl_xor(v[r], JL);
        float mn = fminf(v[r], pv), mx = fmaxf(v[r], pv);
        v[r] = keep_min ? mn : mx;
    }
}

#define INL6(K) pass_inlane<32,K>(v,lane); pass_inlane<16,K>(v,lane); \
                pass_inlane<8,K>(v,lane);  pass_inlane<4,K>(v,lane);  \
                pass_inlane<2,K>(v,lane);  pass_inlane<1,K>(v,lane)

__device__ void sort4096(float v[64], int lane) {
    pass_inlane<1,2>(v,lane);
    pass_inlane<2,4>(v,lane); pass_inlane<1,4>(v,lane);
    pass_inlane<4,8>(v,lane); pass_inlane<2,8>(v,lane); pass_inlane<1,8>(v,lane);
    pass_inlane<8,16>(v,lane); pass_inlane<4,16>(v,lane); pass_inlane<2,16>(v,lane); pass_inlane<1,16>(v,lane);
    pass_inlane<16,32>(v,lane); pass_inlane<8,32>(v,lane); pass_inlane<4,32>(v,lane); pass_inlane<2,32>(v,lane); pass_inlane<1,32>(v,lane);
    INL6(64);
    pass_cross<1,128>(v,lane);  INL6(128);
    pass_cross<2,256>(v,lane);  pass_cross<1,256>(v,lane);  INL6(256);
    pass_cross<4,512>(v,lane);  pass_cross<2,512>(v,lane);  pass_cross<1,512>(v,lane);  INL6(512);
    pass_cross<8,1024>(v,lane); pass_cross<4,1024>(v,lane); pass_cross<2,1024>(v,lane); pass_cross<1,1024>(v,lane); INL6(1024);
    pass_cross<16,2048>(v,lane); pass_cross<8,2048>(v,lane); pass_cross<4,2048>(v,lane); pass_cross<2,2048>(v,lane); pass_cross<1,2048>(v,lane); INL6(2048);
    pass_cross<32,4096>(v,lane); pass_cross<16,4096>(v,lane); pass_cross<8,4096>(v,lane); pass_cross<4,4096>(v,lane); pass_cross<2,4096>(v,lane); pass_cross<1,4096>(v,lane); INL6(4096);
}

__global__ __launch_bounds__(64) void sort_kernel(
        const float* __restrict__ P, const float* __restrict__ wgT,
        float* __restrict__ out) {
    int blk = blockIdx.x;
    int b = blk / DGRAPH, e = blk % DGRAPH;
    int lane = threadIdx.x;
    __shared__ float lds[C_TOT + 36];    // +1 pad per 64 to kill bank conflicts

    const float* row = P + ((size_t)b * DGRAPH + e) * C_TOT;
    for (int g = lane; g < C_TOT; g += 64) lds[g + (g >> 6)] = row[g];
    __syncthreads();

    float v[64];
    #pragma unroll
    for (int r = 0; r < 64; r++) {
        int g = lane * 64 + r;
        v[r] = (g < C_TOT) ? lds[lane * 65 + r] : FLT_MAX;
    }

    sort4096(v, lane);
    __syncthreads();

    const float* wrow = wgT + (size_t)e * C_TOT;
    for (int g = lane; g < C_TOT; g += 64) lds[g + (g >> 6)] = wrow[g];
    __syncthreads();

    float acc = 0.f;
    #pragma unroll
    for (int r = 0; r < 64; r++) {
        int g = lane * 64 + r;
        if (g < C_TOT) acc += v[r] * lds[lane * 65 + r];
    }
    #pragma unroll
    for (int m = 32; m >= 1; m >>= 1) acc += __shfl_xor(acc, m);
    if (lane == 0) out[b * DGRAPH + e] = acc;
}

// ---------------- launch ----------------

extern "C" void kernel_launch(void* const* d_in, const int* in_sizes, int n_in,
                              void* d_out, int out_size, void* d_ws, size_t ws_size,
                              hipStream_t stream) {
    const float* x       = (const float*)d_in[0];
    const float* A_comb  = (const float*)d_in[1];
    const float* w_comb  = (const float*)d_in[2];
    const float* A_graph = (const float*)d_in[3];
    const float* w_graph = (const float*)d_in[4];
    float* out = (float*)d_out;

    float* ws  = (float*)d_ws;
    float* xc  = ws;                          // 576
    float* wgT = xc + 576;                    // 289*2256 = 651,984
    float* gvR = wgT + 651984;                // 4*2256*288 = 2,598,912
    float* P   = gvR + 2598912;               // 4*289*2256 = 2,607,936
    // total ~23.4 MB

    center_kernel<<<12, 64, 0, stream>>>(x, xc);
    transpose_tiled<<<dim3((C_TOT + 31) / 32, (DGRAPH + 31) / 32), 256, 0, stream>>>(
        w_graph, wgT, C_TOT, DGRAPH);
    pair_kernel<<<BATCH * C_TOT, 64, 0, stream>>>(xc, A_comb, w_comb, gvR);
    proj_gemm<<<dim3(36, 5, BATCH), 256, 0, stream>>>(gvR, A_graph, P);
    sort_kernel<<<BATCH * DGRAPH, 64, 0, stream>>>(P, wgT, out);
}

// Round 3
// 214.187 us; speedup vs baseline: 1.6805x; 1.5089x over previous
//
#include <hip/hip_runtime.h>
#include <float.h>

#define N_PTS   48
#define N_PAIRS 1128
#define C_TOT   2256
#define NE      46
#define DOC     277
#define DCOMB   286
#define GSTRIDE 288
#define DGRAPH  289
#define BATCH   4

// ---------------- prep kernels ----------------

__global__ void center_kernel(const float* __restrict__ x, float* __restrict__ xc) {
    int row = blockIdx.x;              // 12 rows = b*3+d
    int t = threadIdx.x;               // 64 threads
    float v = (t < N_PTS) ? x[row * N_PTS + t] : 0.f;
    float s = v;
    #pragma unroll
    for (int m = 32; m >= 1; m >>= 1) s += __shfl_xor(s, m);
    if (t < N_PTS) xc[row * N_PTS + t] = v - s * (1.0f / N_PTS);
}

// LDS-tiled transpose: out[c*R + r] = in[r*C + c]
__global__ __launch_bounds__(256) void transpose_tiled(const float* __restrict__ in,
                                                       float* __restrict__ out, int R, int C) {
    __shared__ float tile[32][33];
    int r0 = blockIdx.x * 32, c0 = blockIdx.y * 32;
    int tx = threadIdx.x & 31, ty = threadIdx.x >> 5;   // 32 x 8
    #pragma unroll
    for (int yy = 0; yy < 4; yy++) {
        int r = r0 + ty + 8 * yy, c = c0 + tx;
        tile[ty + 8 * yy][tx] = (r < R && c < C) ? in[r * C + c] : 0.f;
    }
    __syncthreads();
    #pragma unroll
    for (int yy = 0; yy < 4; yy++) {
        int c = c0 + ty + 8 * yy, r = r0 + tx;
        if (c < C && r < R) out[(size_t)c * R + r] = tile[tx][ty + 8 * yy];
    }
}

// ---------------- stage 1: per-pair kernel ----------------

__device__ __forceinline__ void ce_asc(float& a, float& b) {
    float mn = fminf(a, b), mx = fmaxf(a, b);
    a = mn; b = mx;
}

// Batcher odd-even mergesort on 64 slots, pruned to NE=46 real elements.
// Network is ascending-only (min -> lower index), so any CE with upper
// index >= NE is a provable no-op given +inf pads: prune at compile time.
// Positions 0..45 end up sorted ascending; pads never materialized.
__device__ __forceinline__ void batcher46(float a[NE]) {
    #pragma unroll
    for (int p = 1; p < 64; p <<= 1) {
        #pragma unroll
        for (int k = p; k >= 1; k >>= 1) {
            #pragma unroll
            for (int j = k % p; j + k < 64; j += 2 * k) {
                #pragma unroll
                for (int i = 0; i < k; i++) {
                    int lo = i + j, hi = i + j + k;
                    if (hi < NE && (lo / (2 * p)) == (hi / (2 * p)))
                        ce_asc(a[lo], a[hi]);
                }
            }
        }
    }
}

__global__ __launch_bounds__(64) void pair_kernel(
        const float* __restrict__ xc, const float* __restrict__ A_comb,
        const float* __restrict__ w_comb, float* __restrict__ gvR) {
    int blk = blockIdx.x;
    int b = blk / C_TOT, c = blk % C_TOT;
    int t = threadIdx.x;

    __shared__ float Xs[3][N_PTS];
    __shared__ float MtVs[3][NE];
    __shared__ float Ms[3][3];
    __shared__ float rowv[GSTRIDE];

    for (int idx = t; idx < 3 * N_PTS; idx += 64)
        ((float*)Xs)[idx] = xc[b * 3 * N_PTS + idx];
    if (t < 2) rowv[DCOMB + t] = 0.f;
    __syncthreads();

    // decode ordered pair c -> (first, second); i<j is the sorted pair
    int cc = c % N_PAIRS;
    bool rev = c >= N_PAIRS;
    int i = 0, rem = cc;
    while (rem >= N_PTS - 1 - i) { rem -= N_PTS - 1 - i; i++; }
    int j = i + 1 + rem;
    int first = rev ? j : i, second = rev ? i : j;

    float a0 = Xs[0][first], a1 = Xs[1][first], a2 = Xs[2][first];
    float b0 = Xs[0][second], b1 = Xs[1][second], b2 = Xs[2][second];
    float c0 = a1 * b2 - a2 * b1;
    float c1 = a2 * b0 - a0 * b2;
    float c2 = a0 * b1 - a1 * b0;

    if (t == 0) {
        Ms[0][0] = a0; Ms[0][1] = a1; Ms[0][2] = a2;
        Ms[1][0] = b0; Ms[1][1] = b1; Ms[1][2] = b2;
        Ms[2][0] = c0; Ms[2][1] = c1; Ms[2][2] = c2;
    }
    if (t < NE) {
        int m = t;
        int a = (m < i) ? m : m + 1;     // complement index (skip i, then j; i<j)
        a = (a < j) ? a : a + 1;
        float v0 = Xs[0][a], v1 = Xs[1][a], v2 = Xs[2][a];
        MtVs[0][t] = a0 * v0 + a1 * v1 + a2 * v2;
        MtVs[1][t] = b0 * v0 + b1 * v1 + b2 * v2;
        MtVs[2][t] = c0 * v0 + c1 * v1 + c2 * v2;
    }
    __syncthreads();

    if (t < 9) {                         // vec1 = MtM flattened [k][l]
        int k = t / 3, l = t % 3;
        rowv[t] = Ms[k][0] * Ms[l][0] + Ms[k][1] * Ms[l][1] + Ms[k][2] * Ms[l][2];
    }

    for (int e = t; e < DOC; e += 64) {
        float A0 = A_comb[e], A1 = A_comb[DOC + e], A2 = A_comb[2 * DOC + e];
        float p[NE];
        #pragma unroll
        for (int n = 0; n < NE; n++)
            p[n] = A0 * MtVs[0][n] + A1 * MtVs[1][n] + A2 * MtVs[2][n];
        batcher46(p);
        float acc = 0.f;
        #pragma unroll
        for (int n = 0; n < NE; n++) acc += p[n] * w_comb[n * DOC + e];  // coalesced over lanes
        rowv[9 + e] = acc;
    }
    __syncthreads();

    // coalesced row write: gvR[b][c][0..287]
    float* dst = gvR + ((size_t)b * C_TOT + c) * GSTRIDE;
    for (int idx = t; idx < GSTRIDE; idx += 64) dst[idx] = rowv[idx];
}

// ---------------- stage 2a: projection GEMM ----------------
// P[b][e][c] = sum_d A_graph[d][e] * gvR[b][c][d]
#define KT 32

__global__ __launch_bounds__(256) void proj_gemm(
        const float* __restrict__ gvR, const float* __restrict__ A_graph,
        float* __restrict__ P) {
    __shared__ __align__(16) float As[KT][64];
    __shared__ __align__(16) float Gs[KT][68];
    int b = blockIdx.z;
    int e0 = blockIdx.y * 64;
    int c0 = blockIdx.x * 64;
    int tid = threadIdx.x;
    int tx = tid & 15, ty = tid >> 4;
    float acc[4][4] = {};
    const float* gbase = gvR + (size_t)b * C_TOT * GSTRIDE;

    for (int k0 = 0; k0 < GSTRIDE; k0 += KT) {
        #pragma unroll
        for (int o = 0; o < 8; o++) {
            int idx = o * 256 + tid;
            int kk = idx >> 6, ee = idx & 63;
            int k = k0 + kk, E = e0 + ee;
            As[kk][ee] = (k < DCOMB && E < DGRAPH) ? A_graph[k * DGRAPH + E] : 0.f;
        }
        int kk = tid & 31;
        int cb = tid >> 5;   // 0..7
        #pragma unroll
        for (int o = 0; o < 8; o++) {
            int ccol = o * 8 + cb;
            int C = c0 + ccol;
            Gs[kk][ccol] = (C < C_TOT) ? gbase[(size_t)C * GSTRIDE + k0 + kk] : 0.f;
        }
        __syncthreads();
        #pragma unroll
        for (int k = 0; k < KT; k++) {
            float4 av = *(const float4*)&As[k][ty * 4];
            float4 gq = *(const float4*)&Gs[k][tx * 4];
            float ar[4] = {av.x, av.y, av.z, av.w};
            float gr[4] = {gq.x, gq.y, gq.z, gq.w};
            #pragma unroll
            for (int ii = 0; ii < 4; ii++)
                #pragma unroll
                for (int jj = 0; jj < 4; jj++)
                    acc[ii][jj] += ar[ii] * gr[jj];
        }
        __syncthreads();
    }
    #pragma unroll
    for (int ii = 0; ii < 4; ii++) {
        int e = e0 + ty * 4 + ii;
        int c = c0 + tx * 4;
        if (e < DGRAPH && c < C_TOT) {     // C_TOT % 4 == 0 -> full float4 in-range
            float4 val = make_float4(acc[ii][0], acc[ii][1], acc[ii][2], acc[ii][3]);
            *(float4*)&P[((size_t)b * DGRAPH + e) * C_TOT + c] = val;
        }
    }
}

// ---------------- stage 2b: 4-wave in-register bitonic sort + dot ----------------
// 256 threads, thread owns g = tid*16 + r (16 consecutive slots of 4096).
// 2256 = 141*16 -> threads 0..140 real, 141..255 all-pad.
// j<16: in-thread. 16<=j<=512: __shfl_xor (jl=j/16 <= 32, within wave).
// j>=1024: LDS exchange (3 passes only).

#define RPT 16
#define LSTRIDE 17

template<int J, int K>
__device__ __forceinline__ void bpass_in(float v[RPT], int tid) {
    bool upt = ((tid & (K >> 4)) == 0);          // valid for K>=16
    #pragma unroll
    for (int r = 0; r < RPT; r++) {
        int l = r ^ J;
        if (l > r) {
            bool up = (K < 16) ? ((r & K) == 0) : upt;
            float a = v[r], b = v[l];
            float mn = fminf(a, b), mx = fmaxf(a, b);
            v[r] = up ? mn : mx;
            v[l] = up ? mx : mn;
        }
    }
}

template<int JL, int K>   // exchange with lane tid^JL (JL<=32), block size K>=32
__device__ __forceinline__ void bpass_shfl(float v[RPT], int tid) {
    bool lower = (tid & JL) == 0;
    bool up = (tid & (K >> 4)) == 0;
    bool keep_min = (lower == up);
    #pragma unroll
    for (int r = 0; r < RPT; r++) {
        float pv = __shfl_xor(v[r], JL);
        float mn = fminf(v[r], pv), mx = fmaxf(v[r], pv);
        v[r] = keep_min ? mn : mx;
    }
}

template<int JL, int K>   // cross-wave exchange via LDS (JL = 64 or 128)
__device__ __forceinline__ void bpass_lds(float v[RPT], int tid, float* lds) {
    __syncthreads();
    #pragma unroll
    for (int r = 0; r < RPT; r++) lds[tid * LSTRIDE + r] = v[r];
    __syncthreads();
    bool lower = (tid & JL) == 0;
    bool up = (tid & (K >> 4)) == 0;
    bool keep_min = (lower == up);
    int pbase = (tid ^ JL) * LSTRIDE;
    #pragma unroll
    for (int r = 0; r < RPT; r++) {
        float pv = lds[pbase + r];
        float mn = fminf(v[r], pv), mx = fmaxf(v[r], pv);
        v[r] = keep_min ? mn : mx;
    }
}

#define BIN4(K) bpass_in<8,K>(v,tid); bpass_in<4,K>(v,tid); \
                bpass_in<2,K>(v,tid); bpass_in<1,K>(v,tid)

__global__ __launch_bounds__(256) void sort_kernel(
        const float* __restrict__ P, const float* __restrict__ wgT,
        float* __restrict__ out) {
    int blk = blockIdx.x;
    int b = blk / DGRAPH, e = blk % DGRAPH;
    int tid = threadIdx.x;
    __shared__ float lds[256 * LSTRIDE];
    __shared__ float red[4];

    float v[RPT];
    const float* row = P + ((size_t)b * DGRAPH + e) * C_TOT;
    if (tid < 141) {
        const float4* r4 = (const float4*)(row + tid * RPT);
        #pragma unroll
        for (int q = 0; q < 4; q++) {
            float4 tq = r4[q];
            v[q * 4 + 0] = tq.x; v[q * 4 + 1] = tq.y;
            v[q * 4 + 2] = tq.z; v[q * 4 + 3] = tq.w;
        }
    } else {
        #pragma unroll
        for (int r = 0; r < RPT; r++) v[r] = FLT_MAX;
    }

    // bitonic-4096
    bpass_in<1,2>(v,tid);
    bpass_in<2,4>(v,tid); bpass_in<1,4>(v,tid);
    bpass_in<4,8>(v,tid); bpass_in<2,8>(v,tid); bpass_in<1,8>(v,tid);
    bpass_in<8,16>(v,tid); bpass_in<4,16>(v,tid); bpass_in<2,16>(v,tid); bpass_in<1,16>(v,tid);
    bpass_shfl<1,32>(v,tid);  BIN4(32);
    bpass_shfl<2,64>(v,tid);  bpass_shfl<1,64>(v,tid);  BIN4(64);
    bpass_shfl<4,128>(v,tid); bpass_shfl<2,128>(v,tid); bpass_shfl<1,128>(v,tid); BIN4(128);
    bpass_shfl<8,256>(v,tid); bpass_shfl<4,256>(v,tid); bpass_shfl<2,256>(v,tid); bpass_shfl<1,256>(v,tid); BIN4(256);
    bpass_shfl<16,512>(v,tid); bpass_shfl<8,512>(v,tid); bpass_shfl<4,512>(v,tid); bpass_shfl<2,512>(v,tid); bpass_shfl<1,512>(v,tid); BIN4(512);
    bpass_shfl<32,1024>(v,tid); bpass_shfl<16,1024>(v,tid); bpass_shfl<8,1024>(v,tid); bpass_shfl<4,1024>(v,tid); bpass_shfl<2,1024>(v,tid); bpass_shfl<1,1024>(v,tid); BIN4(1024);
    bpass_lds<64,2048>(v,tid,lds);
    bpass_shfl<32,2048>(v,tid); bpass_shfl<16,2048>(v,tid); bpass_shfl<8,2048>(v,tid); bpass_shfl<4,2048>(v,tid); bpass_shfl<2,2048>(v,tid); bpass_shfl<1,2048>(v,tid); BIN4(2048);
    bpass_lds<128,4096>(v,tid,lds);
    bpass_lds<64,4096>(v,tid,lds);
    bpass_shfl<32,4096>(v,tid); bpass_shfl<16,4096>(v,tid); bpass_shfl<8,4096>(v,tid); bpass_shfl<4,4096>(v,tid); bpass_shfl<2,4096>(v,tid); bpass_shfl<1,4096>(v,tid); BIN4(4096);

    // dot with w (sorted position g = tid*16+r)
    float acc = 0.f;
    if (tid < 141) {
        const float4* w4 = (const float4*)(wgT + (size_t)e * C_TOT + tid * RPT);
        #pragma unroll
        for (int q = 0; q < 4; q++) {
            float4 tq = w4[q];
            acc += v[q * 4 + 0] * tq.x + v[q * 4 + 1] * tq.y
                 + v[q * 4 + 2] * tq.z + v[q * 4 + 3] * tq.w;
        }
    }
    #pragma unroll
    for (int m = 32; m >= 1; m >>= 1) acc += __shfl_xor(acc, m);
    int wave = tid >> 6, lane = tid & 63;
    if (lane == 0) red[wave] = acc;
    __syncthreads();
    if (tid == 0) out[b * DGRAPH + e] = red[0] + red[1] + red[2] + red[3];
}

// ---------------- launch ----------------

extern "C" void kernel_launch(void* const* d_in, const int* in_sizes, int n_in,
                              void* d_out, int out_size, void* d_ws, size_t ws_size,
                              hipStream_t stream) {
    const float* x       = (const float*)d_in[0];
    const float* A_comb  = (const float*)d_in[1];
    const float* w_comb  = (const float*)d_in[2];
    const float* A_graph = (const float*)d_in[3];
    const float* w_graph = (const float*)d_in[4];
    float* out = (float*)d_out;

    float* ws  = (float*)d_ws;
    float* xc  = ws;                          // 576
    float* wgT = xc + 576;                    // 289*2256 = 651,984
    float* gvR = wgT + 651984;                // 4*2256*288 = 2,598,912
    float* P   = gvR + 2598912;               // 4*289*2256 = 2,607,936
    // total ~23.4 MB

    center_kernel<<<12, 64, 0, stream>>>(x, xc);
    transpose_tiled<<<dim3((C_TOT + 31) / 32, (DGRAPH + 31) / 32), 256, 0, stream>>>(
        w_graph, wgT, C_TOT, DGRAPH);
    pair_kernel<<<BATCH * C_TOT, 64, 0, stream>>>(xc, A_comb, w_comb, gvR);
    proj_gemm<<<dim3(36, 5, BATCH), 256, 0, stream>>>(gvR, A_graph, P);
    sort_kernel<<<BATCH * DGRAPH, 256, 0, stream>>>(P, wgT, out);
}

// Round 4
// 193.199 us; speedup vs baseline: 1.8630x; 1.1086x over previous
//
#include <hip/hip_runtime.h>
#include <float.h>

#define N_PTS   48
#define N_PAIRS 1128
#define C_TOT   2256
#define NE      46
#define DOC     277
#define DCOMB   286
#define GSTRIDE 288
#define DGRAPH  289
#define BATCH   4

// ---------------- prep kernels ----------------

__global__ void center_kernel(const float* __restrict__ x, float* __restrict__ xc) {
    int row = blockIdx.x;              // 12 rows = b*3+d
    int t = threadIdx.x;               // 64 threads
    float v = (t < N_PTS) ? x[row * N_PTS + t] : 0.f;
    float s = v;
    #pragma unroll
    for (int m = 32; m >= 1; m >>= 1) s += __shfl_xor(s, m);
    if (t < N_PTS) xc[row * N_PTS + t] = v - s * (1.0f / N_PTS);
}

// LDS-tiled transpose: out[c*R + r] = in[r*C + c]
__global__ __launch_bounds__(256) void transpose_tiled(const float* __restrict__ in,
                                                       float* __restrict__ out, int R, int C) {
    __shared__ float tile[32][33];
    int r0 = blockIdx.x * 32, c0 = blockIdx.y * 32;
    int tx = threadIdx.x & 31, ty = threadIdx.x >> 5;   // 32 x 8
    #pragma unroll
    for (int yy = 0; yy < 4; yy++) {
        int r = r0 + ty + 8 * yy, c = c0 + tx;
        tile[ty + 8 * yy][tx] = (r < R && c < C) ? in[r * C + c] : 0.f;
    }
    __syncthreads();
    #pragma unroll
    for (int yy = 0; yy < 4; yy++) {
        int c = c0 + ty + 8 * yy, r = r0 + tx;
        if (c < C && r < R) out[(size_t)c * R + r] = tile[tx][ty + 8 * yy];
    }
}

// ---------------- stage 1: per-pair kernel ----------------

__device__ __forceinline__ void ce_asc(float& a, float& b) {
    float mn = fminf(a, b), mx = fmaxf(a, b);
    a = mn; b = mx;
}

// Batcher odd-even mergesort on 64 slots, pruned to NE=46 real elements.
// Network is ascending-only (min -> lower index), so any CE with upper
// index >= NE is a provable no-op given +inf pads: prune at compile time.
__device__ __forceinline__ void batcher46(float a[NE]) {
    #pragma unroll
    for (int p = 1; p < 64; p <<= 1) {
        #pragma unroll
        for (int k = p; k >= 1; k >>= 1) {
            #pragma unroll
            for (int j = k % p; j + k < 64; j += 2 * k) {
                #pragma unroll
                for (int i = 0; i < k; i++) {
                    int lo = i + j, hi = i + j + k;
                    if (hi < NE && (lo / (2 * p)) == (hi / (2 * p)))
                        ce_asc(a[lo], a[hi]);
                }
            }
        }
    }
}

// 256 threads per block, one c per block. Thread tid sorts e=tid; threads
// 0..20 additionally sort e=256+tid. Direct coalesced stores, no row staging.
__global__ __launch_bounds__(256, 3) void pair_kernel(
        const float* __restrict__ xc, const float* __restrict__ A_comb,
        const float* __restrict__ w_comb, float* __restrict__ gvR) {
    int blk = blockIdx.x;
    int b = blk / C_TOT, c = blk % C_TOT;
    int tid = threadIdx.x;

    __shared__ float Xs[3][N_PTS];
    __shared__ float MtVs[3][NE + 2];

    if (tid < 3 * N_PTS) ((float*)Xs)[tid] = xc[b * 3 * N_PTS + tid];
    __syncthreads();

    // decode ordered pair c -> (first, second); i<j is the sorted pair
    int cc = c % N_PAIRS;
    bool rev = c >= N_PAIRS;
    int i = 0, rem = cc;
    while (rem >= N_PTS - 1 - i) { rem -= N_PTS - 1 - i; i++; }
    int j = i + 1 + rem;
    int first = rev ? j : i, second = rev ? i : j;

    float a0 = Xs[0][first], a1 = Xs[1][first], a2 = Xs[2][first];
    float b0 = Xs[0][second], b1 = Xs[1][second], b2 = Xs[2][second];
    float c0 = a1 * b2 - a2 * b1;
    float c1 = a2 * b0 - a0 * b2;
    float c2 = a0 * b1 - a1 * b0;

    if (tid < NE) {
        int m = tid;
        int a = (m < i) ? m : m + 1;     // complement index (skip i, then j; i<j)
        a = (a < j) ? a : a + 1;
        float v0 = Xs[0][a], v1 = Xs[1][a], v2 = Xs[2][a];
        MtVs[0][tid] = a0 * v0 + a1 * v1 + a2 * v2;
        MtVs[1][tid] = b0 * v0 + b1 * v1 + b2 * v2;
        MtVs[2][tid] = c0 * v0 + c1 * v1 + c2 * v2;
    }
    __syncthreads();

    float* dst = gvR + ((size_t)b * C_TOT + c) * GSTRIDE;

    if (tid < 9) {                       // vec1 = MtM flattened [k][l]
        float M[3][3] = {{a0, a1, a2}, {b0, b1, b2}, {c0, c1, c2}};
        int k = tid / 3, l = tid % 3;
        dst[tid] = M[k][0] * M[l][0] + M[k][1] * M[l][1] + M[k][2] * M[l][2];
    }
    if (tid >= 9 && tid < 11) dst[DCOMB + tid - 9] = 0.f;   // pad cols 286,287

    // first sort: e = tid (always < 277 since 256 < 277)
    {
        int e = tid;
        float A0 = A_comb[e], A1 = A_comb[DOC + e], A2 = A_comb[2 * DOC + e];
        float p[NE];
        #pragma unroll
        for (int n = 0; n < NE; n++)
            p[n] = A0 * MtVs[0][n] + A1 * MtVs[1][n] + A2 * MtVs[2][n];
        batcher46(p);
        float acc = 0.f;
        #pragma unroll
        for (int n = 0; n < NE; n++) acc += p[n] * w_comb[n * DOC + e];
        dst[9 + e] = acc;
    }
    // tail sort: e = 256 + tid for tid < 21
    if (tid < DOC - 256) {
        int e = 256 + tid;
        float A0 = A_comb[e], A1 = A_comb[DOC + e], A2 = A_comb[2 * DOC + e];
        float p[NE];
        #pragma unroll
        for (int n = 0; n < NE; n++)
            p[n] = A0 * MtVs[0][n] + A1 * MtVs[1][n] + A2 * MtVs[2][n];
        batcher46(p);
        float acc = 0.f;
        #pragma unroll
        for (int n = 0; n < NE; n++) acc += p[n] * w_comb[n * DOC + e];
        dst[9 + e] = acc;
    }
}

// ---------------- stage 2a: projection GEMM ----------------
// P[b][e][c] = sum_d A_graph[d][e] * gvR[b][c][d]
#define KT 32

__global__ __launch_bounds__(256) void proj_gemm(
        const float* __restrict__ gvR, const float* __restrict__ A_graph,
        float* __restrict__ P) {
    __shared__ __align__(16) float As[KT][64];
    __shared__ __align__(16) float Gs[KT][68];
    int b = blockIdx.z;
    int e0 = blockIdx.y * 64;
    int c0 = blockIdx.x * 64;
    int tid = threadIdx.x;
    int tx = tid & 15, ty = tid >> 4;
    float acc[4][4] = {};
    const float* gbase = gvR + (size_t)b * C_TOT * GSTRIDE;

    for (int k0 = 0; k0 < GSTRIDE; k0 += KT) {
        #pragma unroll
        for (int o = 0; o < 8; o++) {
            int idx = o * 256 + tid;
            int kk = idx >> 6, ee = idx & 63;
            int k = k0 + kk, E = e0 + ee;
            As[kk][ee] = (k < DCOMB && E < DGRAPH) ? A_graph[k * DGRAPH + E] : 0.f;
        }
        int kk = tid & 31;
        int cb = tid >> 5;   // 0..7
        #pragma unroll
        for (int o = 0; o < 8; o++) {
            int ccol = o * 8 + cb;
            int C = c0 + ccol;
            Gs[kk][ccol] = (C < C_TOT) ? gbase[(size_t)C * GSTRIDE + k0 + kk] : 0.f;
        }
        __syncthreads();
        #pragma unroll
        for (int k = 0; k < KT; k++) {
            float4 av = *(const float4*)&As[k][ty * 4];
            float4 gq = *(const float4*)&Gs[k][tx * 4];
            float ar[4] = {av.x, av.y, av.z, av.w};
            float gr[4] = {gq.x, gq.y, gq.z, gq.w};
            #pragma unroll
            for (int ii = 0; ii < 4; ii++)
                #pragma unroll
                for (int jj = 0; jj < 4; jj++)
                    acc[ii][jj] += ar[ii] * gr[jj];
        }
        __syncthreads();
    }
    #pragma unroll
    for (int ii = 0; ii < 4; ii++) {
        int e = e0 + ty * 4 + ii;
        int c = c0 + tx * 4;
        if (e < DGRAPH && c < C_TOT) {     // C_TOT % 4 == 0 -> full float4 in-range
            float4 val = make_float4(acc[ii][0], acc[ii][1], acc[ii][2], acc[ii][3]);
            *(float4*)&P[((size_t)b * DGRAPH + e) * C_TOT + c] = val;
        }
    }
}

// ---------------- stage 2b: 4-wave in-register bitonic sort + dot ----------------
// 256 threads, thread owns g = tid*16 + r (16 consecutive slots of 4096).
// 2256 = 141*16 -> threads 0..140 real, 141..255 all-pad.

#define RPT 16
#define LSTRIDE 17

template<int J, int K>
__device__ __forceinline__ void bpass_in(float v[RPT], int tid) {
    bool upt = ((tid & (K >> 4)) == 0);          // valid for K>=16
    #pragma unroll
    for (int r = 0; r < RPT; r++) {
        int l = r ^ J;
        if (l > r) {
            bool up = (K < 16) ? ((r & K) == 0) : upt;
            float a = v[r], b = v[l];
            float mn = fminf(a, b), mx = fmaxf(a, b);
            v[r] = up ? mn : mx;
            v[l] = up ? mx : mn;
        }
    }
}

template<int JL, int K>   // exchange with lane tid^JL (JL<=32), block size K>=32
__device__ __forceinline__ void bpass_shfl(float v[RPT], int tid) {
    bool lower = (tid & JL) == 0;
    bool up = (tid & (K >> 4)) == 0;
    bool keep_min = (lower == up);
    #pragma unroll
    for (int r = 0; r < RPT; r++) {
        float pv = __shfl_xor(v[r], JL);
        float mn = fminf(v[r], pv), mx = fmaxf(v[r], pv);
        v[r] = keep_min ? mn : mx;
    }
}

template<int JL, int K>   // cross-wave exchange via LDS (JL = 64 or 128)
__device__ __forceinline__ void bpass_lds(float v[RPT], int tid, float* lds) {
    __syncthreads();
    #pragma unroll
    for (int r = 0; r < RPT; r++) lds[tid * LSTRIDE + r] = v[r];
    __syncthreads();
    bool lower = (tid & JL) == 0;
    bool up = (tid & (K >> 4)) == 0;
    bool keep_min = (lower == up);
    int pbase = (tid ^ JL) * LSTRIDE;
    #pragma unroll
    for (int r = 0; r < RPT; r++) {
        float pv = lds[pbase + r];
        float mn = fminf(v[r], pv), mx = fmaxf(v[r], pv);
        v[r] = keep_min ? mn : mx;
    }
}

#define BIN4(K) bpass_in<8,K>(v,tid); bpass_in<4,K>(v,tid); \
                bpass_in<2,K>(v,tid); bpass_in<1,K>(v,tid)

__global__ __launch_bounds__(256) void sort_kernel(
        const float* __restrict__ P, const float* __restrict__ wgT,
        float* __restrict__ out) {
    int blk = blockIdx.x;
    int b = blk / DGRAPH, e = blk % DGRAPH;
    int tid = threadIdx.x;
    __shared__ float lds[256 * LSTRIDE];
    __shared__ float red[4];

    float v[RPT];
    const float* row = P + ((size_t)b * DGRAPH + e) * C_TOT;
    if (tid < 141) {
        const float4* r4 = (const float4*)(row + tid * RPT);
        #pragma unroll
        for (int q = 0; q < 4; q++) {
            float4 tq = r4[q];
            v[q * 4 + 0] = tq.x; v[q * 4 + 1] = tq.y;
            v[q * 4 + 2] = tq.z; v[q * 4 + 3] = tq.w;
        }
    } else {
        #pragma unroll
        for (int r = 0; r < RPT; r++) v[r] = FLT_MAX;
    }

    // bitonic-4096
    bpass_in<1,2>(v,tid);
    bpass_in<2,4>(v,tid); bpass_in<1,4>(v,tid);
    bpass_in<4,8>(v,tid); bpass_in<2,8>(v,tid); bpass_in<1,8>(v,tid);
    bpass_in<8,16>(v,tid); bpass_in<4,16>(v,tid); bpass_in<2,16>(v,tid); bpass_in<1,16>(v,tid);
    bpass_shfl<1,32>(v,tid);  BIN4(32);
    bpass_shfl<2,64>(v,tid);  bpass_shfl<1,64>(v,tid);  BIN4(64);
    bpass_shfl<4,128>(v,tid); bpass_shfl<2,128>(v,tid); bpass_shfl<1,128>(v,tid); BIN4(128);
    bpass_shfl<8,256>(v,tid); bpass_shfl<4,256>(v,tid); bpass_shfl<2,256>(v,tid); bpass_shfl<1,256>(v,tid); BIN4(256);
    bpass_shfl<16,512>(v,tid); bpass_shfl<8,512>(v,tid); bpass_shfl<4,512>(v,tid); bpass_shfl<2,512>(v,tid); bpass_shfl<1,512>(v,tid); BIN4(512);
    bpass_shfl<32,1024>(v,tid); bpass_shfl<16,1024>(v,tid); bpass_shfl<8,1024>(v,tid); bpass_shfl<4,1024>(v,tid); bpass_shfl<2,1024>(v,tid); bpass_shfl<1,1024>(v,tid); BIN4(1024);
    bpass_lds<64,2048>(v,tid,lds);
    bpass_shfl<32,2048>(v,tid); bpass_shfl<16,2048>(v,tid); bpass_shfl<8,2048>(v,tid); bpass_shfl<4,2048>(v,tid); bpass_shfl<2,2048>(v,tid); bpass_shfl<1,2048>(v,tid); BIN4(2048);
    bpass_lds<128,4096>(v,tid,lds);
    bpass_lds<64,4096>(v,tid,lds);
    bpass_shfl<32,4096>(v,tid); bpass_shfl<16,4096>(v,tid); bpass_shfl<8,4096>(v,tid); bpass_shfl<4,4096>(v,tid); bpass_shfl<2,4096>(v,tid); bpass_shfl<1,4096>(v,tid); BIN4(4096);

    // dot with w (sorted position g = tid*16+r)
    float acc = 0.f;
    if (tid < 141) {
        const float4* w4 = (const float4*)(wgT + (size_t)e * C_TOT + tid * RPT);
        #pragma unroll
        for (int q = 0; q < 4; q++) {
            float4 tq = w4[q];
            acc += v[q * 4 + 0] * tq.x + v[q * 4 + 1] * tq.y
                 + v[q * 4 + 2] * tq.z + v[q * 4 + 3] * tq.w;
        }
    }
    #pragma unroll
    for (int m = 32; m >= 1; m >>= 1) acc += __shfl_xor(acc, m);
    int wave = tid >> 6, lane = tid & 63;
    if (lane == 0) red[wave] = acc;
    __syncthreads();
    if (tid == 0) out[b * DGRAPH + e] = red[0] + red[1] + red[2] + red[3];
}

// ---------------- launch ----------------

extern "C" void kernel_launch(void* const* d_in, const int* in_sizes, int n_in,
                              void* d_out, int out_size, void* d_ws, size_t ws_size,
                              hipStream_t stream) {
    const float* x       = (const float*)d_in[0];
    const float* A_comb  = (const float*)d_in[1];
    const float* w_comb  = (const float*)d_in[2];
    const float* A_graph = (const float*)d_in[3];
    const float* w_graph = (const float*)d_in[4];
    float* out = (float*)d_out;

    float* ws  = (float*)d_ws;
    float* xc  = ws;                          // 576
    float* wgT = xc + 576;                    // 289*2256 = 651,984
    float* gvR = wgT + 651984;                // 4*2256*288 = 2,598,912
    float* P   = gvR + 2598912;               // 4*289*2256 = 2,607,936
    // total ~23.4 MB

    center_kernel<<<12, 64, 0, stream>>>(x, xc);
    transpose_tiled<<<dim3((C_TOT + 31) / 32, (DGRAPH + 31) / 32), 256, 0, stream>>>(
        w_graph, wgT, C_TOT, DGRAPH);
    pair_kernel<<<BATCH * C_TOT, 256, 0, stream>>>(xc, A_comb, w_comb, gvR);
    proj_gemm<<<dim3(36, 5, BATCH), 256, 0, stream>>>(gvR, A_graph, P);
    sort_kernel<<<BATCH * DGRAPH, 256, 0, stream>>>(P, wgT, out);
}